// Round 2
// baseline (1845.117 us; speedup 1.0000x reference)
//
#include <hip/hip_runtime.h>
#include <math.h>

// FNO3D forecaster: B=8, C=3, H=W=64, T=32, WIDTH=32 ch, modes 8x8x8 (4 corners), 4 layers.
// Strategy: partial separable DFT onto the 16x16x8 kept modes instead of full FFTs.
// All tensors fp32 (per reference).
//
// ws layout (floats):
//   X  : 33,554,432  activations [b][c32][y64][x64][t32]
//   T1 : 16,777,216  cplx [b][c][y][x][kt8]      (fwd t-DFT out; reused as inv-x out)
//   T2 :  4,194,304  cplx [b][c][y][kx16][kt8]   (fwd x-DFT out; reused as inv-y out)
//   T3 :  1,048,576  cplx [b][c][ky16][kx16][kt8]
//   T4 :  1,048,576  cplx (mode-mixed)
// total 56,623,104 floats = 226.5 MB

#define TWO_PI 6.2831853071795864769f

__device__ __forceinline__ float gelu_exact(float v) {
    return 0.5f * v * (1.0f + erff(v * 0.70710678118654752f));
}

// ---------------- lift: x_t + grid -> p conv -> X ----------------
__global__ __launch_bounds__(256) void k_lift(const float* __restrict__ xt,
                                              const float* __restrict__ pw,
                                              const float* __restrict__ pb,
                                              float* __restrict__ X) {
    int i = blockIdx.x * 256 + threadIdx.x;     // 33,554,432 total
    int t = i & 31, x = (i >> 5) & 63, y = (i >> 11) & 63, c = (i >> 17) & 31, b = i >> 22;
    int sp = y * 64 + x;
    float a0 = xt[(b * 3 + 0) * 4096 + sp];
    float a1 = xt[(b * 3 + 1) * 4096 + sp];
    float a2 = xt[(b * 3 + 2) * 4096 + sp];
    float gy = y * (1.0f / 63.0f), gx = x * (1.0f / 63.0f), gt = t * (1.0f / 31.0f);
    const float* w = pw + c * 6;
    float v = pb[c] + w[0] * a0 + w[1] * a1 + w[2] * a2
            + w[3] * gy + w[4] * gx + w[5] * gt;
    X[i] = v;
}

// ---------------- forward t-DFT: X -> T1 (8 modes) ----------------
__global__ __launch_bounds__(256) void k_tdft(const float* __restrict__ X, float2* __restrict__ T1) {
    __shared__ float xs[2048];       // 64 x * 32 t
    __shared__ float2 tw[32];
    int g = blockIdx.x;              // (b*32+c)*64 + y ; 16384 blocks
    long base = (long)g * 2048;
    int tid = threadIdx.x;
    for (int k = tid; k < 2048; k += 256) xs[k] = X[base + k];
    if (tid < 32) { float s, c; sincosf(tid * (TWO_PI / 32.0f), &s, &c); tw[tid] = make_float2(c, s); }
    __syncthreads();
    for (int r = 0; r < 2; ++r) {
        int j = tid + r * 256;       // 512 outputs: x*8 + kt
        int x = j >> 3, kt = j & 7;
        const float* col = xs + x * 32;
        float sr = 0.f, si = 0.f;
        for (int t = 0; t < 32; ++t) {
            float2 w = tw[(kt * t) & 31];
            float v = col[t];
            sr += v * w.x;
            si -= v * w.y;
        }
        T1[(long)g * 512 + j] = make_float2(sr, si);
    }
}

// ---------------- forward x-DFT: T1 -> T2 (16 modes) ----------------
__global__ __launch_bounds__(256) void k_xdft(const float2* __restrict__ T1, float2* __restrict__ T2) {
    __shared__ float2 s[1024];       // 2 y-rows x 64 x x 8 kt
    __shared__ float2 tw[64];
    int g = blockIdx.x;              // bc*32 + ypair ; 8192 blocks
    int ypair = g & 31; int bc = g >> 5;
    long base = ((long)bc * 64 + ypair * 2) * 512;
    int tid = threadIdx.x;
    for (int k = tid; k < 1024; k += 256) s[k] = T1[base + k];
    if (tid < 64) { float sn, cs; sincosf(tid * (TWO_PI / 64.0f), &sn, &cs); tw[tid] = make_float2(cs, sn); }
    __syncthreads();
    int half = tid >> 7, jj = tid & 127;
    int kxi = jj >> 3, kt = jj & 7;
    int kx = kxi < 8 ? kxi : kxi + 48;
    const float2* row = s + half * 512;
    float sr = 0.f, si = 0.f;
    for (int x = 0; x < 64; ++x) {
        float2 w = tw[(kx * x) & 63];
        float2 a = row[x * 8 + kt];
        sr += a.x * w.x + a.y * w.y;    // a * e^{-i th}
        si += a.y * w.x - a.x * w.y;
    }
    T2[((long)bc * 64 + ypair * 2 + half) * 128 + jj] = make_float2(sr, si);
}

// ---------------- forward y-DFT: T2 -> T3 (16 modes) ----------------
__global__ __launch_bounds__(128) void k_ydft(const float2* __restrict__ T2, float2* __restrict__ T3) {
    __shared__ float2 s[512];        // 64 y x 8 kt
    __shared__ float2 tw[64];
    int g = blockIdx.x;              // bc*16 + kx ; 4096 blocks
    int kx = g & 15; int bc = g >> 4;
    int tid = threadIdx.x;           // 128
    for (int k = tid; k < 512; k += 128) {
        int y = k >> 3, kt = k & 7;
        s[k] = T2[((long)bc * 64 + y) * 128 + kx * 8 + kt];
    }
    if (tid < 64) { float sn, cs; sincosf(tid * (TWO_PI / 64.0f), &sn, &cs); tw[tid] = make_float2(cs, sn); }
    __syncthreads();
    int kyi = tid >> 3, kt = tid & 7;
    int ky = kyi < 8 ? kyi : kyi + 48;
    float sr = 0.f, si = 0.f;
    for (int y = 0; y < 64; ++y) {
        float2 w = tw[(ky * y) & 63];
        float2 a = s[y * 8 + kt];
        sr += a.x * w.x + a.y * w.y;
        si += a.y * w.x - a.x * w.y;
    }
    T3[((long)bc * 256 + kyi * 16 + kx) * 8 + kt] = make_float2(sr, si);
}

// ---------------- mode mix: T3 x W -> T4 ----------------
__global__ __launch_bounds__(256) void k_mix(const float2* __restrict__ T3,
                                             const float* __restrict__ wr,
                                             const float* __restrict__ wi,
                                             float2* __restrict__ T4, int layer) {
    __shared__ float2 s[256];        // [i=32][kt=8]
    int g = blockIdx.x;              // b*256 + (ky*16+kx) ; 2048 blocks
    int mode = g & 255; int b = g >> 8;
    int kyi = mode >> 4, kxi = mode & 15;
    int tid = threadIdx.x;
    {
        int i = tid >> 3, kt = tid & 7;
        s[tid] = T3[((long)(b * 32 + i) * 256 + mode) * 8 + kt];
    }
    __syncthreads();
    int corner = (kyi >= 8 ? 1 : 0) + (kxi >= 8 ? 2 : 0);
    long wbase = (long)(layer * 4 + corner) * 524288 + (long)(kyi & 7) * 64 + (long)(kxi & 7) * 8;
    int o = tid >> 3, kt = tid & 7;
    long wb = wbase + (long)o * 512 + kt;
    float sr = 0.f, si = 0.f;
    for (int i = 0; i < 32; ++i) {
        float2 a = s[i * 8 + kt];
        long widx = wb + (long)i * 16384;
        float r = wr[widx], im = wi[widx];
        sr += a.x * r - a.y * im;
        si += a.x * im + a.y * r;
    }
    T4[((long)(b * 32 + o) * 256 + mode) * 8 + kt] = make_float2(sr, si);
}

// ---------------- inverse y: T4 -> T2 space ----------------
__global__ __launch_bounds__(256) void k_invy(const float2* __restrict__ T4, float2* __restrict__ T5) {
    __shared__ float2 s[128];        // 16 ky x 8 kt
    __shared__ float2 tw[64];
    int g = blockIdx.x;              // bc*16 + kx ; 4096 blocks
    int kx = g & 15; int bc = g >> 4;
    int tid = threadIdx.x;
    if (tid < 128) {
        int kyi = tid >> 3, kt = tid & 7;
        s[tid] = T4[((long)bc * 256 + kyi * 16 + kx) * 8 + kt];
    } else if (tid < 192) {
        int m = tid - 128; float sn, cs; sincosf(m * (TWO_PI / 64.0f), &sn, &cs); tw[m] = make_float2(cs, sn);
    }
    __syncthreads();
    for (int r = 0; r < 2; ++r) {
        int j = tid + r * 256;       // y*8 + kt, 512 outputs
        int y = j >> 3, kt = j & 7;
        float sr = 0.f, si = 0.f;
        for (int kyi = 0; kyi < 16; ++kyi) {
            int ky = kyi < 8 ? kyi : kyi + 48;
            float2 w = tw[(ky * y) & 63];
            float2 a = s[kyi * 8 + kt];
            sr += a.x * w.x - a.y * w.y;   // a * e^{+i th}
            si += a.y * w.x + a.x * w.y;
        }
        T5[((long)bc * 64 + y) * 128 + kx * 8 + kt] = make_float2(sr, si);
    }
}

// ---------------- inverse x: T2 space -> T1 space ----------------
__global__ __launch_bounds__(256) void k_invx(const float2* __restrict__ T5, float2* __restrict__ T6) {
    __shared__ float2 s[128];        // 16 kx x 8 kt
    __shared__ float2 tw[64];
    int g = blockIdx.x;              // bc*64 + y ; 16384 blocks
    int tid = threadIdx.x;
    if (tid < 128) {
        s[tid] = T5[(long)g * 128 + tid];
    } else if (tid < 192) {
        int m = tid - 128; float sn, cs; sincosf(m * (TWO_PI / 64.0f), &sn, &cs); tw[m] = make_float2(cs, sn);
    }
    __syncthreads();
    for (int r = 0; r < 2; ++r) {
        int j = tid + r * 256;       // x*8 + kt, 512 outputs
        int x = j >> 3, kt = j & 7;
        float sr = 0.f, si = 0.f;
        for (int kxi = 0; kxi < 16; ++kxi) {
            int kx = kxi < 8 ? kxi : kxi + 48;
            float2 w = tw[(kx * x) & 63];
            float2 a = s[kxi * 8 + kt];
            sr += a.x * w.x - a.y * w.y;
            si += a.y * w.x + a.x * w.y;
        }
        T6[(long)g * 512 + j] = make_float2(sr, si);
    }
}

// ------- fused: inverse-t + pointwise conv + add + GELU, in-place on X -------
__global__ __launch_bounds__(256) void k_fuse(float* __restrict__ X, const float2* __restrict__ T6,
                                              const float* __restrict__ pww,
                                              const float* __restrict__ pwb, int layer) {
    __shared__ float xs[1024];       // [i=32][t=32]
    __shared__ float2 ss[256];       // [o=32][kt=8]
    __shared__ float wsh[1024];      // [o][i]
    __shared__ float bsh[32];
    __shared__ float2 tw[32];
    int g = blockIdx.x;              // b*4096 + (y*64+x) ; 32768 blocks
    int sp = g & 4095; int b = g >> 12;
    int tid = threadIdx.x;
    for (int k = tid; k < 1024; k += 256) {
        int i = k >> 5, t = k & 31;
        xs[k] = X[((long)(b * 32 + i) * 4096 + sp) * 32 + t];
    }
    {
        int o = tid >> 3, kt = tid & 7;
        ss[tid] = T6[((long)(b * 32 + o) * 4096 + sp) * 8 + kt];
    }
    for (int k = tid; k < 1024; k += 256) wsh[k] = pww[(long)layer * 1024 + k];
    if (tid < 32) {
        bsh[tid] = pwb[layer * 32 + tid];
        float sn, cs; sincosf(tid * (TWO_PI / 32.0f), &sn, &cs); tw[tid] = make_float2(cs, sn);
    }
    __syncthreads();
    for (int r = 0; r < 4; ++r) {
        int j = tid + r * 256;       // o*32 + t, 1024 outputs
        int o = j >> 5, t = j & 31;
        const float2* so = ss + o * 8;
        // irfft over t: Re(F0) + 2*sum Re(Fk e^{+i 2pi k t/32}); bins 8..16 zero
        float acc = so[0].x;
        for (int kt = 1; kt < 8; ++kt) {
            float2 w = tw[(kt * t) & 31];
            acc += 2.0f * (so[kt].x * w.x - so[kt].y * w.y);
        }
        acc *= (1.0f / 131072.0f);   // 1/(64*64*32)
        const float* wo = wsh + o * 32;
        float pv = bsh[o];
        for (int i = 0; i < 32; ++i) pv += wo[i] * xs[i * 32 + t];
        X[((long)(b * 32 + o) * 4096 + sp) * 32 + t] = gelu_exact(acc + pv);
    }
}

// ---------------- head: q1 + gelu + q2, write fp32 transposed out ----------------
__global__ __launch_bounds__(256) void k_head(const float* __restrict__ X,
                                              const float* __restrict__ q1w,
                                              const float* __restrict__ q1b,
                                              const float* __restrict__ q2w,
                                              const float* __restrict__ q2b,
                                              float* __restrict__ out) {
    __shared__ float xs[1024];       // [i=32][t=32]
    __shared__ float h[2048];        // [o=64][t=32]
    __shared__ float w1[2048];
    __shared__ float w2[192];
    __shared__ float b1[64];
    __shared__ float b2v[3];
    int g = blockIdx.x;              // b*4096 + sp ; 32768 blocks
    int sp = g & 4095; int b = g >> 12;
    int tid = threadIdx.x;
    for (int k = tid; k < 1024; k += 256) {
        int i = k >> 5, t = k & 31;
        xs[k] = X[((long)(b * 32 + i) * 4096 + sp) * 32 + t];
    }
    for (int k = tid; k < 2048; k += 256) w1[k] = q1w[k];
    if (tid < 192) w2[tid] = q2w[tid];
    if (tid < 64) b1[tid] = q1b[tid];
    if (tid < 3)  b2v[tid] = q2b[tid];
    __syncthreads();
    for (int r = 0; r < 8; ++r) {
        int j = tid + r * 256;       // o*32 + t, 2048
        int o = j >> 5, t = j & 31;
        float v = b1[o];
        const float* wo = w1 + o * 32;
        for (int i = 0; i < 32; ++i) v += wo[i] * xs[i * 32 + t];
        h[j] = gelu_exact(v);
    }
    __syncthreads();
    if (tid < 96) {
        int c = tid >> 5, t = tid & 31;
        float v = b2v[c];
        for (int o = 0; o < 64; ++o) v += w2[c * 64 + o] * h[o * 32 + t];
        out[((long)(b * 32 + t) * 3 + c) * 4096 + sp] = v;
    }
}

extern "C" void kernel_launch(void* const* d_in, const int* in_sizes, int n_in,
                              void* d_out, int out_size, void* d_ws, size_t ws_size,
                              hipStream_t stream) {
    const float* xt  = (const float*)d_in[0];
    const float* pw  = (const float*)d_in[1];
    const float* pb  = (const float*)d_in[2];
    const float* swr = (const float*)d_in[3];
    const float* swi = (const float*)d_in[4];
    const float* pww = (const float*)d_in[5];
    const float* pwb = (const float*)d_in[6];
    const float* q1w = (const float*)d_in[7];
    const float* q1b = (const float*)d_in[8];
    const float* q2w = (const float*)d_in[9];
    const float* q2b = (const float*)d_in[10];
    float* out = (float*)d_out;

    float*  X  = (float*)d_ws;                       // 33,554,432 floats
    float2* T1 = (float2*)(X + 33554432);            // 8,388,608 cplx
    float2* T2 = (float2*)((float*)T1 + 16777216);   // 2,097,152 cplx
    float2* T3 = (float2*)((float*)T2 + 4194304);    // 524,288 cplx
    float2* T4 = (float2*)((float*)T3 + 1048576);    // 524,288 cplx

    k_lift<<<131072, 256, 0, stream>>>(xt, pw, pb, X);
    for (int l = 0; l < 4; ++l) {
        k_tdft<<<16384, 256, 0, stream>>>(X, T1);
        k_xdft<<<8192, 256, 0, stream>>>(T1, T2);
        k_ydft<<<4096, 128, 0, stream>>>(T2, T3);
        k_mix<<<2048, 256, 0, stream>>>(T3, swr, swi, T4, l);
        k_invy<<<4096, 256, 0, stream>>>(T4, T2);
        k_invx<<<16384, 256, 0, stream>>>(T2, T1);
        k_fuse<<<32768, 256, 0, stream>>>(X, T1, pww, pwb, l);
    }
    k_head<<<32768, 256, 0, stream>>>(X, q1w, q1b, q2w, q2b, out);
}

// Round 3
// 1441.581 us; speedup vs baseline: 1.2799x; 1.2799x over previous
//
#include <hip/hip_runtime.h>
#include <math.h>

// FNO3D: B=8, C=3, H=W=64, T=32, WIDTH=32, modes 8x8x8 (4 corners), 4 layers.
// Round 3: register/SGPR-blocked pointwise (thread owns (sp,t), 32 channel accs,
// weights via wave-uniform scalar loads), Goertzel t-DFT, head fused into last
// layer, mode-major mix with batch loop.
//
// ws layout (floats): X 33,554,432 | T1 16,777,216 | T2 4,194,304 | T3 1,048,576 | T4 1,048,576

#define TWO_PI 6.2831853071795864769f

__device__ __forceinline__ float gelu_exact(float v) {
    return 0.5f * v * (1.0f + erff(v * 0.70710678118654752f));
}

// ---------------- lift: x_t + grid -> p conv -> X ----------------
__global__ __launch_bounds__(256) void k_lift(const float* __restrict__ xt,
                                              const float* __restrict__ pw,
                                              const float* __restrict__ pb,
                                              float* __restrict__ X) {
    int i = blockIdx.x * 256 + threadIdx.x;
    int t = i & 31, x = (i >> 5) & 63, y = (i >> 11) & 63, c = (i >> 17) & 31, b = i >> 22;
    int sp = y * 64 + x;
    float a0 = xt[(b * 3 + 0) * 4096 + sp];
    float a1 = xt[(b * 3 + 1) * 4096 + sp];
    float a2 = xt[(b * 3 + 2) * 4096 + sp];
    float gy = y * (1.0f / 63.0f), gx = x * (1.0f / 63.0f), gt = t * (1.0f / 31.0f);
    const float* w = pw + c * 6;
    float v = pb[c] + w[0] * a0 + w[1] * a1 + w[2] * a2
            + w[3] * gy + w[4] * gx + w[5] * gt;
    X[i] = v;
}

// ------------- forward t-DFT via Goertzel: X -> T1 (8 modes) -------------
// block: (b,c, y-quad); thread = (yloc, x). X_k = e^{j th} s31 - s30, th = 2pi k/32.
__global__ __launch_bounds__(256) void k_tdft_g(const float* __restrict__ X, float2* __restrict__ T1) {
    __shared__ float xs[8448];      // 4*64 rows of 32, padded +1 per row
    int g = blockIdx.x;             // bc*16 + yq ; 4096 blocks
    int yq = g & 15; int bc = g >> 4;
    long base = ((long)bc * 64 + yq * 4) * 2048;
    int tid = threadIdx.x;
    for (int k = tid; k < 8192; k += 256) xs[k + (k >> 5)] = X[base + k];
    __syncthreads();
    int x = tid & 63, yloc = tid >> 6;
    const float* col = xs + (yloc * 64 + x) * 33;
    const float C2[8] = {2.0f, 1.9615705608f, 1.8477590650f, 1.6629392246f,
                         1.4142135624f, 1.1111404660f, 0.7653668647f, 0.3901806440f};
    const float CK[8] = {1.0f, 0.9807852804f, 0.9238795325f, 0.8314696123f,
                         0.7071067812f, 0.5555702330f, 0.3826834324f, 0.1950903220f};
    const float SK[8] = {0.0f, 0.1950903220f, 0.3826834324f, 0.5555702330f,
                         0.7071067812f, 0.8314696123f, 0.9238795325f, 0.9807852804f};
    float s1[8], s2[8];
    #pragma unroll
    for (int k = 0; k < 8; ++k) { s1[k] = 0.f; s2[k] = 0.f; }
    for (int t = 0; t < 32; ++t) {
        float v = col[t];
        #pragma unroll
        for (int k = 0; k < 8; ++k) {
            float s0 = v + C2[k] * s1[k] - s2[k];
            s2[k] = s1[k]; s1[k] = s0;
        }
    }
    long ob = (((long)bc * 64 + yq * 4 + yloc) * 64 + x) * 8;
    #pragma unroll
    for (int k = 0; k < 8; ++k)
        T1[ob + k] = make_float2(CK[k] * s1[k] - s2[k], SK[k] * s1[k]);
}

// ---------------- forward x-DFT: T1 -> T2 (16 modes) ----------------
__global__ __launch_bounds__(256) void k_xdft(const float2* __restrict__ T1, float2* __restrict__ T2) {
    __shared__ float2 s[1024];
    __shared__ float2 tw[64];
    int g = blockIdx.x;              // bc*32 + ypair ; 8192 blocks
    int ypair = g & 31; int bc = g >> 5;
    long base = ((long)bc * 64 + ypair * 2) * 512;
    int tid = threadIdx.x;
    for (int k = tid; k < 1024; k += 256) s[k] = T1[base + k];
    if (tid < 64) { float sn, cs; sincosf(tid * (TWO_PI / 64.0f), &sn, &cs); tw[tid] = make_float2(cs, sn); }
    __syncthreads();
    int half = tid >> 7, jj = tid & 127;
    int kxi = jj >> 3, kt = jj & 7;
    int kx = kxi < 8 ? kxi : kxi + 48;
    const float2* row = s + half * 512;
    float sr = 0.f, si = 0.f;
    for (int x = 0; x < 64; ++x) {
        float2 w = tw[(kx * x) & 63];
        float2 a = row[x * 8 + kt];
        sr += a.x * w.x + a.y * w.y;
        si += a.y * w.x - a.x * w.y;
    }
    T2[((long)bc * 64 + ypair * 2 + half) * 128 + jj] = make_float2(sr, si);
}

// ---------------- forward y-DFT: T2 -> T3 (16 modes) ----------------
__global__ __launch_bounds__(128) void k_ydft(const float2* __restrict__ T2, float2* __restrict__ T3) {
    __shared__ float2 s[512];
    __shared__ float2 tw[64];
    int g = blockIdx.x;              // bc*16 + kx ; 4096 blocks
    int kx = g & 15; int bc = g >> 4;
    int tid = threadIdx.x;
    for (int k = tid; k < 512; k += 128) {
        int y = k >> 3, kt = k & 7;
        s[k] = T2[((long)bc * 64 + y) * 128 + kx * 8 + kt];
    }
    if (tid < 64) { float sn, cs; sincosf(tid * (TWO_PI / 64.0f), &sn, &cs); tw[tid] = make_float2(cs, sn); }
    __syncthreads();
    int kyi = tid >> 3, kt = tid & 7;
    int ky = kyi < 8 ? kyi : kyi + 48;
    float sr = 0.f, si = 0.f;
    for (int y = 0; y < 64; ++y) {
        float2 w = tw[(ky * y) & 63];
        float2 a = s[y * 8 + kt];
        sr += a.x * w.x + a.y * w.y;
        si += a.y * w.x - a.x * w.y;
    }
    T3[((long)bc * 256 + kyi * 16 + kx) * 8 + kt] = make_float2(sr, si);
}

// -------- mode mix (mode-major, b-loop amortizes weight reads): T3 x W -> T4 --------
__global__ __launch_bounds__(256) void k_mix2(const float2* __restrict__ T3,
                                              const float* __restrict__ wr,
                                              const float* __restrict__ wi,
                                              float2* __restrict__ T4, int layer) {
    __shared__ float2 s[2304];       // [i=32][b=8] rows padded to 9 f2
    int mode = blockIdx.x;           // 256 blocks
    int kyi = mode >> 4, kxi = mode & 15;
    int tid = threadIdx.x;
    {
        int bb = tid >> 5, i = tid & 31;
        const float2* src = T3 + ((long)(bb * 32 + i) * 256 + mode) * 8;
        float2* dst = s + (i * 8 + bb) * 9;
        #pragma unroll
        for (int k = 0; k < 8; ++k) dst[k] = src[k];
    }
    __syncthreads();
    int corner = (kyi >= 8 ? 1 : 0) + (kxi >= 8 ? 2 : 0);
    long wbase = (long)(layer * 4 + corner) * 524288 + (long)(kyi & 7) * 64 + (long)(kxi & 7) * 8;
    int o = tid >> 3, kt = tid & 7;
    long wb = wbase + (long)o * 512 + kt;
    float2 acc[8];
    #pragma unroll
    for (int bb = 0; bb < 8; ++bb) acc[bb] = make_float2(0.f, 0.f);
    for (int i = 0; i < 32; ++i) {
        float r = wr[wb + (long)i * 16384], im = wi[wb + (long)i * 16384];
        #pragma unroll
        for (int bb = 0; bb < 8; ++bb) {
            float2 a = s[(i * 8 + bb) * 9 + kt];
            acc[bb].x += a.x * r - a.y * im;
            acc[bb].y += a.x * im + a.y * r;
        }
    }
    #pragma unroll
    for (int bb = 0; bb < 8; ++bb)
        T4[((long)(bb * 32 + o) * 256 + mode) * 8 + kt] = acc[bb];
}

// ---------------- inverse y: T4 -> T2 space ----------------
__global__ __launch_bounds__(256) void k_invy(const float2* __restrict__ T4, float2* __restrict__ T5) {
    __shared__ float2 s[128];
    __shared__ float2 tw[64];
    int g = blockIdx.x;              // bc*16 + kx ; 4096 blocks
    int kx = g & 15; int bc = g >> 4;
    int tid = threadIdx.x;
    if (tid < 128) {
        int kyi = tid >> 3, kt = tid & 7;
        s[tid] = T4[((long)bc * 256 + kyi * 16 + kx) * 8 + kt];
    } else if (tid < 192) {
        int m = tid - 128; float sn, cs; sincosf(m * (TWO_PI / 64.0f), &sn, &cs); tw[m] = make_float2(cs, sn);
    }
    __syncthreads();
    for (int r = 0; r < 2; ++r) {
        int j = tid + r * 256;
        int y = j >> 3, kt = j & 7;
        float sr = 0.f, si = 0.f;
        for (int kyi = 0; kyi < 16; ++kyi) {
            int ky = kyi < 8 ? kyi : kyi + 48;
            float2 w = tw[(ky * y) & 63];
            float2 a = s[kyi * 8 + kt];
            sr += a.x * w.x - a.y * w.y;
            si += a.y * w.x + a.x * w.y;
        }
        T5[((long)bc * 64 + y) * 128 + kx * 8 + kt] = make_float2(sr, si);
    }
}

// ---------------- inverse x: T2 space -> T1 space ----------------
__global__ __launch_bounds__(256) void k_invx(const float2* __restrict__ T5, float2* __restrict__ T6) {
    __shared__ float2 s[128];
    __shared__ float2 tw[64];
    int g = blockIdx.x;              // bc*64 + y ; 16384 blocks
    int tid = threadIdx.x;
    if (tid < 128) {
        s[tid] = T5[(long)g * 128 + tid];
    } else if (tid < 192) {
        int m = tid - 128; float sn, cs; sincosf(m * (TWO_PI / 64.0f), &sn, &cs); tw[m] = make_float2(cs, sn);
    }
    __syncthreads();
    for (int r = 0; r < 2; ++r) {
        int j = tid + r * 256;
        int x = j >> 3, kt = j & 7;
        float sr = 0.f, si = 0.f;
        for (int kxi = 0; kxi < 16; ++kxi) {
            int kx = kxi < 8 ? kxi : kxi + 48;
            float2 w = tw[(kx * x) & 63];
            float2 a = s[kxi * 8 + kt];
            sr += a.x * w.x - a.y * w.y;
            si += a.y * w.x + a.x * w.y;
        }
        T6[(long)g * 512 + j] = make_float2(sr, si);
    }
}

// ------- fuse2: thread owns (sp,t); 32 channel accs in VGPRs; weights via s_load;
//         spectral irfft-t from small LDS tile; gelu; in-place X update -------
__global__ __launch_bounds__(256) void k_fuse2(float* __restrict__ X, const float2* __restrict__ T6,
                                               const float* __restrict__ pww,
                                               const float* __restrict__ pwb, int layer) {
    __shared__ float2 ts[2112];      // [o=32] rows of 64 f2 padded to 66
    int g = blockIdx.x;              // b*512 + spt ; 4096 blocks
    int spt = g & 511; int b = g >> 9;
    int sp0 = spt * 8;
    int tid = threadIdx.x;
    {
        int o = tid >> 3, spl = tid & 7;
        const float2* src = T6 + ((long)(b * 32 + o) * 4096 + sp0 + spl) * 8;
        float2* dst = ts + o * 66 + spl * 8;
        #pragma unroll
        for (int k = 0; k < 8; ++k) dst[k] = src[k];
    }
    __syncthreads();
    int t = tid & 31, spl = tid >> 5;
    int sp = sp0 + spl;
    // twiddles e^{+j 2pi k t/32}, k=1..7
    float ck[8], sk[8];
    float c1, s1v; sincosf(t * (TWO_PI / 32.0f), &s1v, &c1);
    ck[1] = c1; sk[1] = s1v;
    float pc = c1, ps = s1v;
    #pragma unroll
    for (int k = 2; k < 8; ++k) {
        float nc = pc * c1 - ps * s1v;
        float ns = ps * c1 + pc * s1v;
        ck[k] = nc; sk[k] = ns; pc = nc; ps = ns;
    }
    const float* wl = pww + layer * 1024;
    const float* bl = pwb + layer * 32;
    float acc[32];
    #pragma unroll
    for (int o = 0; o < 32; ++o) acc[o] = bl[o];
    long xbase = ((long)b * 32 * 4096 + sp) * 32 + t;
    #pragma unroll
    for (int i = 0; i < 32; ++i) {
        float xv = X[xbase + (long)i * 131072];
        #pragma unroll
        for (int o = 0; o < 32; ++o) acc[o] += wl[o * 32 + i] * xv;
    }
    #pragma unroll
    for (int o = 0; o < 32; ++o) {
        const float2* f = ts + o * 66 + spl * 8;
        float spr = f[0].x;
        #pragma unroll
        for (int k = 1; k < 8; ++k) spr += 2.0f * (f[k].x * ck[k] - f[k].y * sk[k]);
        float v = acc[o] + spr * (1.0f / 131072.0f);
        X[((long)(b * 32 + o) * 4096 + sp) * 32 + t] = gelu_exact(v);
    }
}

// ------- fuse2_last: layer 3 + full head (q1,gelu,q2) in registers -> out -------
__global__ __launch_bounds__(256) void k_fuse2_last(const float* __restrict__ X, const float2* __restrict__ T6,
                                                    const float* __restrict__ pww, const float* __restrict__ pwb,
                                                    const float* __restrict__ q1w, const float* __restrict__ q1b,
                                                    const float* __restrict__ q2w, const float* __restrict__ q2b,
                                                    float* __restrict__ out) {
    __shared__ float2 ts[2112];
    int g = blockIdx.x;              // b*512 + spt ; 4096 blocks
    int spt = g & 511; int b = g >> 9;
    int sp0 = spt * 8;
    int tid = threadIdx.x;
    {
        int o = tid >> 3, spl = tid & 7;
        const float2* src = T6 + ((long)(b * 32 + o) * 4096 + sp0 + spl) * 8;
        float2* dst = ts + o * 66 + spl * 8;
        #pragma unroll
        for (int k = 0; k < 8; ++k) dst[k] = src[k];
    }
    __syncthreads();
    int t = tid & 31, spl = tid >> 5;
    int sp = sp0 + spl;
    float ck[8], sk[8];
    float c1, s1v; sincosf(t * (TWO_PI / 32.0f), &s1v, &c1);
    ck[1] = c1; sk[1] = s1v;
    float pc = c1, ps = s1v;
    #pragma unroll
    for (int k = 2; k < 8; ++k) {
        float nc = pc * c1 - ps * s1v;
        float ns = ps * c1 + pc * s1v;
        ck[k] = nc; sk[k] = ns; pc = nc; ps = ns;
    }
    const int layer = 3;
    const float* wl = pww + layer * 1024;
    const float* bl = pwb + layer * 32;
    float acc[32];
    #pragma unroll
    for (int o = 0; o < 32; ++o) acc[o] = bl[o];
    long xbase = ((long)b * 32 * 4096 + sp) * 32 + t;
    #pragma unroll
    for (int i = 0; i < 32; ++i) {
        float xv = X[xbase + (long)i * 131072];
        #pragma unroll
        for (int o = 0; o < 32; ++o) acc[o] += wl[o * 32 + i] * xv;
    }
    #pragma unroll
    for (int o = 0; o < 32; ++o) {
        const float2* f = ts + o * 66 + spl * 8;
        float spr = f[0].x;
        #pragma unroll
        for (int k = 1; k < 8; ++k) spr += 2.0f * (f[k].x * ck[k] - f[k].y * sk[k]);
        acc[o] = gelu_exact(acc[o] + spr * (1.0f / 131072.0f));
    }
    // head, all weights scalar-loaded
    float o0 = q2b[0], o1 = q2b[1], o2 = q2b[2];
    #pragma unroll
    for (int j = 0; j < 64; ++j) {
        float h = q1b[j];
        #pragma unroll
        for (int i = 0; i < 32; ++i) h += q1w[j * 32 + i] * acc[i];
        h = gelu_exact(h);
        o0 += q2w[j] * h;
        o1 += q2w[64 + j] * h;
        o2 += q2w[128 + j] * h;
    }
    // stage through LDS for coalesced out writes
    float* st = (float*)ts;
    __syncthreads();
    st[(t * 3 + 0) * 8 + spl] = o0;
    st[(t * 3 + 1) * 8 + spl] = o1;
    st[(t * 3 + 2) * 8 + spl] = o2;
    __syncthreads();
    int t2 = tid >> 3, spl2 = tid & 7;
    #pragma unroll
    for (int c = 0; c < 3; ++c)
        out[((long)(b * 32 + t2) * 3 + c) * 4096 + sp0 + spl2] = st[(t2 * 3 + c) * 8 + spl2];
}

extern "C" void kernel_launch(void* const* d_in, const int* in_sizes, int n_in,
                              void* d_out, int out_size, void* d_ws, size_t ws_size,
                              hipStream_t stream) {
    const float* xt  = (const float*)d_in[0];
    const float* pw  = (const float*)d_in[1];
    const float* pb  = (const float*)d_in[2];
    const float* swr = (const float*)d_in[3];
    const float* swi = (const float*)d_in[4];
    const float* pww = (const float*)d_in[5];
    const float* pwb = (const float*)d_in[6];
    const float* q1w = (const float*)d_in[7];
    const float* q1b = (const float*)d_in[8];
    const float* q2w = (const float*)d_in[9];
    const float* q2b = (const float*)d_in[10];
    float* out = (float*)d_out;

    float*  X  = (float*)d_ws;
    float2* T1 = (float2*)(X + 33554432);
    float2* T2 = (float2*)((float*)T1 + 16777216);
    float2* T3 = (float2*)((float*)T2 + 4194304);
    float2* T4 = (float2*)((float*)T3 + 1048576);

    k_lift<<<131072, 256, 0, stream>>>(xt, pw, pb, X);
    for (int l = 0; l < 4; ++l) {
        k_tdft_g<<<4096, 256, 0, stream>>>(X, T1);
        k_xdft<<<8192, 256, 0, stream>>>(T1, T2);
        k_ydft<<<4096, 128, 0, stream>>>(T2, T3);
        k_mix2<<<256, 256, 0, stream>>>(T3, swr, swi, T4, l);
        k_invy<<<4096, 256, 0, stream>>>(T4, T2);
        k_invx<<<16384, 256, 0, stream>>>(T2, T1);
        if (l < 3)
            k_fuse2<<<4096, 256, 0, stream>>>(X, T1, pww, pwb, l);
        else
            k_fuse2_last<<<4096, 256, 0, stream>>>(X, T1, pww, pwb, q1w, q1b, q2w, q2b, out);
    }
}

// Round 4
// 1204.436 us; speedup vs baseline: 1.5319x; 1.1969x over previous
//
#include <hip/hip_runtime.h>
#include <math.h>

// FNO3D: B=8, C=3, H=W=64, T=32, WIDTH=32, modes 8x8x8 (4 corners), 4 layers.
// Round 4: X layout [b][sp][t][c] (channel-innermost, float4-vectorized),
// Goertzel t-DFT fused into lift & fuse epilogues (k_tdft gone), padded LDS
// staging (conflict-free), head fused into last layer.
//
// ws floats: X 33,554,432 | T1 16,777,216 | T2 4,194,304 | T3 1,048,576 | T4 1,048,576

#define TWO_PI 6.2831853071795864769f

__device__ __forceinline__ float gelu_exact(float v) {
    return 0.5f * v * (1.0f + erff(v * 0.70710678118654752f));
}

// Goertzel constants for N=32, k=0..7
#define GOERTZEL_CONSTS \
    const float C2[8] = {2.0f, 1.9615705608f, 1.8477590650f, 1.6629392246f, \
                         1.4142135624f, 1.1111404660f, 0.7653668647f, 0.3901806440f}; \
    const float CK[8] = {1.0f, 0.9807852804f, 0.9238795325f, 0.8314696123f, \
                         0.7071067812f, 0.5555702330f, 0.3826834324f, 0.1950903220f}; \
    const float SK[8] = {0.0f, 0.1950903220f, 0.3826834324f, 0.5555702330f, \
                         0.7071067812f, 0.8314696123f, 0.9238795325f, 0.9807852804f};

// ---- lift: x_t + grid -> p conv -> X [b][sp][t][c]; fused Goertzel -> T1 ----
__global__ __launch_bounds__(256) void k_lift(const float* __restrict__ xt,
                                              const float* __restrict__ pw,
                                              const float* __restrict__ pb,
                                              float* __restrict__ X,
                                              float2* __restrict__ T1) {
    __shared__ float xs[8448];          // [spl8][t32] rows of 33 (pad)
    int g = blockIdx.x;                 // b*512 + spt ; 4096 blocks
    int spt = g & 511, b = g >> 9;
    int sp0 = spt * 8;
    int y = sp0 >> 6, x0 = sp0 & 63;
    int tid = threadIdx.x;
    int t = tid & 31, spl = tid >> 5;
    int sp = sp0 + spl;
    float a0 = xt[(b * 3 + 0) * 4096 + sp];
    float a1 = xt[(b * 3 + 1) * 4096 + sp];
    float a2 = xt[(b * 3 + 2) * 4096 + sp];
    float gy = y * (1.0f / 63.0f), gx = (x0 + spl) * (1.0f / 63.0f), gt = t * (1.0f / 31.0f);
    float v[32];
    #pragma unroll
    for (int c = 0; c < 32; ++c) {
        const float* w = pw + c * 6;
        v[c] = pb[c] + w[0] * a0 + w[1] * a1 + w[2] * a2
             + w[3] * gy + w[4] * gx + w[5] * gt;
    }
    float* xg = X + (((long)(b * 4096 + sp)) * 32 + t) * 32;
    #pragma unroll
    for (int j = 0; j < 8; ++j)
        ((float4*)xg)[j] = make_float4(v[4*j], v[4*j+1], v[4*j+2], v[4*j+3]);
    float* row = xs + (spl * 32 + t) * 33;
    #pragma unroll
    for (int c = 0; c < 32; ++c) row[c] = v[c];
    __syncthreads();
    // Goertzel over t for (c, spl)
    int c = tid & 31, sl = tid >> 5;
    GOERTZEL_CONSTS
    float s1[8], s2[8];
    #pragma unroll
    for (int k = 0; k < 8; ++k) { s1[k] = 0.f; s2[k] = 0.f; }
    const float* col = xs + (sl * 32) * 33 + c;
    for (int tt = 0; tt < 32; ++tt) {
        float xv = col[tt * 33];
        #pragma unroll
        for (int k = 0; k < 8; ++k) {
            float s0 = xv + C2[k] * s1[k] - s2[k];
            s2[k] = s1[k]; s1[k] = s0;
        }
    }
    float2* ob = T1 + ((long)(b * 32 + c) * 4096 + sp0 + sl) * 8;
    #pragma unroll
    for (int k = 0; k < 8; ++k)
        ob[k] = make_float2(CK[k] * s1[k] - s2[k], SK[k] * s1[k]);
}

// ---------------- forward x-DFT: T1 -> T2 (16 modes) ----------------
__global__ __launch_bounds__(256) void k_xdft(const float2* __restrict__ T1, float2* __restrict__ T2) {
    __shared__ float2 s[1024];
    __shared__ float2 tw[64];
    int g = blockIdx.x;              // bc*32 + ypair ; 8192 blocks
    int ypair = g & 31; int bc = g >> 5;
    long base = ((long)bc * 64 + ypair * 2) * 512;
    int tid = threadIdx.x;
    for (int k = tid; k < 1024; k += 256) s[k] = T1[base + k];
    if (tid < 64) { float sn, cs; sincosf(tid * (TWO_PI / 64.0f), &sn, &cs); tw[tid] = make_float2(cs, sn); }
    __syncthreads();
    int half = tid >> 7, jj = tid & 127;
    int kxi = jj >> 3, kt = jj & 7;
    int kx = kxi < 8 ? kxi : kxi + 48;
    const float2* row = s + half * 512;
    float sr = 0.f, si = 0.f;
    for (int x = 0; x < 64; ++x) {
        float2 w = tw[(kx * x) & 63];
        float2 a = row[x * 8 + kt];
        sr += a.x * w.x + a.y * w.y;
        si += a.y * w.x - a.x * w.y;
    }
    T2[((long)bc * 64 + ypair * 2 + half) * 128 + jj] = make_float2(sr, si);
}

// ---------------- forward y-DFT: T2 -> T3 (16 modes) ----------------
__global__ __launch_bounds__(128) void k_ydft(const float2* __restrict__ T2, float2* __restrict__ T3) {
    __shared__ float2 s[512];
    __shared__ float2 tw[64];
    int g = blockIdx.x;              // bc*16 + kx ; 4096 blocks
    int kx = g & 15; int bc = g >> 4;
    int tid = threadIdx.x;
    for (int k = tid; k < 512; k += 128) {
        int y = k >> 3, kt = k & 7;
        s[k] = T2[((long)bc * 64 + y) * 128 + kx * 8 + kt];
    }
    if (tid < 64) { float sn, cs; sincosf(tid * (TWO_PI / 64.0f), &sn, &cs); tw[tid] = make_float2(cs, sn); }
    __syncthreads();
    int kyi = tid >> 3, kt = tid & 7;
    int ky = kyi < 8 ? kyi : kyi + 48;
    float sr = 0.f, si = 0.f;
    for (int y = 0; y < 64; ++y) {
        float2 w = tw[(ky * y) & 63];
        float2 a = s[y * 8 + kt];
        sr += a.x * w.x + a.y * w.y;
        si += a.y * w.x - a.x * w.y;
    }
    T3[((long)bc * 256 + kyi * 16 + kx) * 8 + kt] = make_float2(sr, si);
}

// -------- mode mix (mode-major, b-loop amortizes weight reads) --------
__global__ __launch_bounds__(256) void k_mix2(const float2* __restrict__ T3,
                                              const float* __restrict__ wr,
                                              const float* __restrict__ wi,
                                              float2* __restrict__ T4, int layer) {
    __shared__ float2 s[2304];       // [i=32][b=8] rows padded to 9 f2
    int mode = blockIdx.x;           // 256 blocks
    int kyi = mode >> 4, kxi = mode & 15;
    int tid = threadIdx.x;
    {
        int bb = tid >> 5, i = tid & 31;
        const float2* src = T3 + ((long)(bb * 32 + i) * 256 + mode) * 8;
        float2* dst = s + (i * 8 + bb) * 9;
        #pragma unroll
        for (int k = 0; k < 8; ++k) dst[k] = src[k];
    }
    __syncthreads();
    int corner = (kyi >= 8 ? 1 : 0) + (kxi >= 8 ? 2 : 0);
    long wbase = (long)(layer * 4 + corner) * 524288 + (long)(kyi & 7) * 64 + (long)(kxi & 7) * 8;
    int o = tid >> 3, kt = tid & 7;
    long wb = wbase + (long)o * 512 + kt;
    float2 acc[8];
    #pragma unroll
    for (int bb = 0; bb < 8; ++bb) acc[bb] = make_float2(0.f, 0.f);
    for (int i = 0; i < 32; ++i) {
        float r = wr[wb + (long)i * 16384], im = wi[wb + (long)i * 16384];
        #pragma unroll
        for (int bb = 0; bb < 8; ++bb) {
            float2 a = s[(i * 8 + bb) * 9 + kt];
            acc[bb].x += a.x * r - a.y * im;
            acc[bb].y += a.x * im + a.y * r;
        }
    }
    #pragma unroll
    for (int bb = 0; bb < 8; ++bb)
        T4[((long)(bb * 32 + o) * 256 + mode) * 8 + kt] = acc[bb];
}

// ---------------- inverse y: T4 -> T2 space ----------------
__global__ __launch_bounds__(256) void k_invy(const float2* __restrict__ T4, float2* __restrict__ T5) {
    __shared__ float2 s[128];
    __shared__ float2 tw[64];
    int g = blockIdx.x;              // bc*16 + kx ; 4096 blocks
    int kx = g & 15; int bc = g >> 4;
    int tid = threadIdx.x;
    if (tid < 128) {
        int kyi = tid >> 3, kt = tid & 7;
        s[tid] = T4[((long)bc * 256 + kyi * 16 + kx) * 8 + kt];
    } else if (tid < 192) {
        int m = tid - 128; float sn, cs; sincosf(m * (TWO_PI / 64.0f), &sn, &cs); tw[m] = make_float2(cs, sn);
    }
    __syncthreads();
    for (int r = 0; r < 2; ++r) {
        int j = tid + r * 256;
        int y = j >> 3, kt = j & 7;
        float sr = 0.f, si = 0.f;
        for (int kyi = 0; kyi < 16; ++kyi) {
            int ky = kyi < 8 ? kyi : kyi + 48;
            float2 w = tw[(ky * y) & 63];
            float2 a = s[kyi * 8 + kt];
            sr += a.x * w.x - a.y * w.y;
            si += a.y * w.x + a.x * w.y;
        }
        T5[((long)bc * 64 + y) * 128 + kx * 8 + kt] = make_float2(sr, si);
    }
}

// ---------------- inverse x: T2 space -> T1 space (T6) ----------------
__global__ __launch_bounds__(256) void k_invx(const float2* __restrict__ T5, float2* __restrict__ T6) {
    __shared__ float2 s[128];
    __shared__ float2 tw[64];
    int g = blockIdx.x;              // bc*64 + y ; 16384 blocks
    int tid = threadIdx.x;
    if (tid < 128) {
        s[tid] = T5[(long)g * 128 + tid];
    } else if (tid < 192) {
        int m = tid - 128; float sn, cs; sincosf(m * (TWO_PI / 64.0f), &sn, &cs); tw[m] = make_float2(cs, sn);
    }
    __syncthreads();
    for (int r = 0; r < 2; ++r) {
        int j = tid + r * 256;
        int x = j >> 3, kt = j & 7;
        float sr = 0.f, si = 0.f;
        for (int kxi = 0; kxi < 16; ++kxi) {
            int kx = kxi < 8 ? kxi : kxi + 48;
            float2 w = tw[(kx * x) & 63];
            float2 a = s[kxi * 8 + kt];
            sr += a.x * w.x - a.y * w.y;
            si += a.y * w.x + a.x * w.y;
        }
        T6[(long)g * 512 + j] = make_float2(sr, si);
    }
}

// ---- fuse2: pointwise (float4 X) + irfft-t + gelu, in-place X; Goertzel -> T1 ----
__global__ __launch_bounds__(256) void k_fuse2(float* __restrict__ X, const float2* __restrict__ T6,
                                               const float* __restrict__ pww,
                                               const float* __restrict__ pwb,
                                               float2* __restrict__ T1, int layer) {
    __shared__ float smem[8448];     // union: ts (2112 f2 = 16896B) / xs (8448 f)
    float2* ts = (float2*)smem;
    int g = blockIdx.x;              // b*512 + spt ; 4096 blocks
    int spt = g & 511, b = g >> 9;
    int sp0 = spt * 8;
    int tid = threadIdx.x;
    {   // stage spectral tile: ts[o][spl][kt], rows of 66 f2
        int o = tid >> 3, spl8 = tid & 7;
        const float4* src = (const float4*)(T6 + ((long)(b * 32 + o) * 4096 + sp0 + spl8) * 8);
        float4* dst = (float4*)(ts + o * 66 + spl8 * 8);
        #pragma unroll
        for (int j = 0; j < 4; ++j) dst[j] = src[j];
    }
    __syncthreads();
    int t = tid & 31, spl = tid >> 5;
    int sp = sp0 + spl;
    // twiddles e^{+j 2pi k t/32}
    float ck[8], sk[8];
    float c1, s1v; sincosf(t * (TWO_PI / 32.0f), &s1v, &c1);
    ck[1] = c1; sk[1] = s1v;
    float pc = c1, ps = s1v;
    #pragma unroll
    for (int k = 2; k < 8; ++k) {
        float nc = pc * c1 - ps * s1v, ns = ps * c1 + pc * s1v;
        ck[k] = nc; sk[k] = ns; pc = nc; ps = ns;
    }
    const float* wl = pww + layer * 1024;
    const float* bl = pwb + layer * 32;
    float* xg = X + (((long)(b * 4096 + sp)) * 32 + t) * 32;
    float x[32];
    #pragma unroll
    for (int j = 0; j < 8; ++j) {
        float4 q = ((const float4*)xg)[j];
        x[4*j] = q.x; x[4*j+1] = q.y; x[4*j+2] = q.z; x[4*j+3] = q.w;
    }
    float acc[32];
    #pragma unroll
    for (int o = 0; o < 32; ++o) acc[o] = bl[o];
    #pragma unroll
    for (int i = 0; i < 32; ++i) {
        float xv = x[i];
        #pragma unroll
        for (int o = 0; o < 32; ++o) acc[o] += wl[o * 32 + i] * xv;
    }
    #pragma unroll
    for (int o = 0; o < 32; ++o) {
        const float2* f = ts + o * 66 + spl * 8;
        float spr = f[0].x;
        #pragma unroll
        for (int k = 1; k < 8; ++k) spr += 2.0f * (f[k].x * ck[k] - f[k].y * sk[k]);
        acc[o] = gelu_exact(acc[o] + spr * (1.0f / 131072.0f));
    }
    #pragma unroll
    for (int j = 0; j < 8; ++j)
        ((float4*)xg)[j] = make_float4(acc[4*j], acc[4*j+1], acc[4*j+2], acc[4*j+3]);
    __syncthreads();                  // ts reads done; reuse smem as xs
    float* row = smem + (spl * 32 + t) * 33;
    #pragma unroll
    for (int c = 0; c < 32; ++c) row[c] = acc[c];
    __syncthreads();
    // Goertzel t-DFT for next layer
    int c = tid & 31, sl = tid >> 5;
    GOERTZEL_CONSTS
    float s1[8], s2[8];
    #pragma unroll
    for (int k = 0; k < 8; ++k) { s1[k] = 0.f; s2[k] = 0.f; }
    const float* col = smem + (sl * 32) * 33 + c;
    for (int tt = 0; tt < 32; ++tt) {
        float xv = col[tt * 33];
        #pragma unroll
        for (int k = 0; k < 8; ++k) {
            float s0 = xv + C2[k] * s1[k] - s2[k];
            s2[k] = s1[k]; s1[k] = s0;
        }
    }
    float2* ob = T1 + ((long)(b * 32 + c) * 4096 + sp0 + sl) * 8;
    #pragma unroll
    for (int k = 0; k < 8; ++k)
        ob[k] = make_float2(CK[k] * s1[k] - s2[k], SK[k] * s1[k]);
}

// ---- fuse2_last: layer 3 + head (q1,gelu,q2) -> out ----
__global__ __launch_bounds__(256) void k_fuse2_last(const float* __restrict__ X, const float2* __restrict__ T6,
                                                    const float* __restrict__ pww, const float* __restrict__ pwb,
                                                    const float* __restrict__ q1w, const float* __restrict__ q1b,
                                                    const float* __restrict__ q2w, const float* __restrict__ q2b,
                                                    float* __restrict__ out) {
    __shared__ float smem[4224];     // ts 2112 f2 / st 864 f
    float2* ts = (float2*)smem;
    int g = blockIdx.x;              // b*512 + spt ; 4096 blocks
    int spt = g & 511, b = g >> 9;
    int sp0 = spt * 8;
    int tid = threadIdx.x;
    {
        int o = tid >> 3, spl8 = tid & 7;
        const float4* src = (const float4*)(T6 + ((long)(b * 32 + o) * 4096 + sp0 + spl8) * 8);
        float4* dst = (float4*)(ts + o * 66 + spl8 * 8);
        #pragma unroll
        for (int j = 0; j < 4; ++j) dst[j] = src[j];
    }
    __syncthreads();
    int t = tid & 31, spl = tid >> 5;
    int sp = sp0 + spl;
    float ck[8], sk[8];
    float c1, s1v; sincosf(t * (TWO_PI / 32.0f), &s1v, &c1);
    ck[1] = c1; sk[1] = s1v;
    float pc = c1, ps = s1v;
    #pragma unroll
    for (int k = 2; k < 8; ++k) {
        float nc = pc * c1 - ps * s1v, ns = ps * c1 + pc * s1v;
        ck[k] = nc; sk[k] = ns; pc = nc; ps = ns;
    }
    const float* wl = pww + 3 * 1024;
    const float* bl = pwb + 3 * 32;
    const float* xg = X + (((long)(b * 4096 + sp)) * 32 + t) * 32;
    float x[32];
    #pragma unroll
    for (int j = 0; j < 8; ++j) {
        float4 q = ((const float4*)xg)[j];
        x[4*j] = q.x; x[4*j+1] = q.y; x[4*j+2] = q.z; x[4*j+3] = q.w;
    }
    float acc[32];
    #pragma unroll
    for (int o = 0; o < 32; ++o) acc[o] = bl[o];
    #pragma unroll
    for (int i = 0; i < 32; ++i) {
        float xv = x[i];
        #pragma unroll
        for (int o = 0; o < 32; ++o) acc[o] += wl[o * 32 + i] * xv;
    }
    #pragma unroll
    for (int o = 0; o < 32; ++o) {
        const float2* f = ts + o * 66 + spl * 8;
        float spr = f[0].x;
        #pragma unroll
        for (int k = 1; k < 8; ++k) spr += 2.0f * (f[k].x * ck[k] - f[k].y * sk[k]);
        acc[o] = gelu_exact(acc[o] + spr * (1.0f / 131072.0f));
    }
    // head
    float o0 = q2b[0], o1 = q2b[1], o2 = q2b[2];
    #pragma unroll
    for (int j = 0; j < 64; ++j) {
        float h = q1b[j];
        #pragma unroll
        for (int i = 0; i < 32; ++i) h += q1w[j * 32 + i] * acc[i];
        h = gelu_exact(h);
        o0 += q2w[j] * h;
        o1 += q2w[64 + j] * h;
        o2 += q2w[128 + j] * h;
    }
    __syncthreads();
    float* st = smem;                // [t][c] rows of 9 (pad): conflict-free
    st[(t * 3 + 0) * 9 + spl] = o0;
    st[(t * 3 + 1) * 9 + spl] = o1;
    st[(t * 3 + 2) * 9 + spl] = o2;
    __syncthreads();
    int t2 = tid >> 3, spl2 = tid & 7;
    #pragma unroll
    for (int c = 0; c < 3; ++c)
        out[((long)(b * 32 + t2) * 3 + c) * 4096 + sp0 + spl2] = st[(t2 * 3 + c) * 9 + spl2];
}

extern "C" void kernel_launch(void* const* d_in, const int* in_sizes, int n_in,
                              void* d_out, int out_size, void* d_ws, size_t ws_size,
                              hipStream_t stream) {
    const float* xt  = (const float*)d_in[0];
    const float* pw  = (const float*)d_in[1];
    const float* pb  = (const float*)d_in[2];
    const float* swr = (const float*)d_in[3];
    const float* swi = (const float*)d_in[4];
    const float* pww = (const float*)d_in[5];
    const float* pwb = (const float*)d_in[6];
    const float* q1w = (const float*)d_in[7];
    const float* q1b = (const float*)d_in[8];
    const float* q2w = (const float*)d_in[9];
    const float* q2b = (const float*)d_in[10];
    float* out = (float*)d_out;

    float*  X  = (float*)d_ws;
    float2* T1 = (float2*)(X + 33554432);
    float2* T2 = (float2*)((float*)T1 + 16777216);
    float2* T3 = (float2*)((float*)T2 + 4194304);
    float2* T4 = (float2*)((float*)T3 + 1048576);

    k_lift<<<4096, 256, 0, stream>>>(xt, pw, pb, X, T1);
    for (int l = 0; l < 4; ++l) {
        k_xdft<<<8192, 256, 0, stream>>>(T1, T2);
        k_ydft<<<4096, 128, 0, stream>>>(T2, T3);
        k_mix2<<<256, 256, 0, stream>>>(T3, swr, swi, T4, l);
        k_invy<<<4096, 256, 0, stream>>>(T4, T2);
        k_invx<<<16384, 256, 0, stream>>>(T2, T1);
        if (l < 3)
            k_fuse2<<<4096, 256, 0, stream>>>(X, T1, pww, pwb, T1, l);
        else
            k_fuse2_last<<<4096, 256, 0, stream>>>(X, T1, pww, pwb, q1w, q1b, q2w, q2b, out);
    }
}